// Round 8
// baseline (586.489 us; speedup 1.0000x reference)
//
#include <hip/hip_runtime.h>

// Problem constants
#define NROWS 16384      // 8 * (8*16*16)
#define NE 8192
#define NCH 64           // k-chunks per row (chunk = 128 k's)
#define CHK 128
#define OUT_LOSS 4194304
#define OUT_IDX  4194305

#define U_MARGIN  2.5e-5f   // u-space np-gap ulp(S1)/2 = 1.53e-5 + screen err + slack
#define CH_MARGIN 3.0e-5f

typedef __attribute__((ext_vector_type(8))) short short8;
typedef __attribute__((ext_vector_type(8))) unsigned short u16x8;
typedef __attribute__((ext_vector_type(4))) float f32x4;

__device__ inline unsigned short bf16_rne(float f) {
    unsigned u = __float_as_uint(f);
    return (unsigned short)((u + 0x7FFFu + ((u >> 16) & 1u)) >> 16);
}

// exact np SSE 4-chain emulation of fl(S1 - 2*P) (sequential, no fma, no reassoc)
__device__ inline float np_dist(const float4* __restrict__ zf4,
                                const float4* __restrict__ ef, float s1v) {
#pragma clang fp contract(off)
    float a0 = 0.f, a1 = 0.f, a2 = 0.f, a3 = 0.f;
#pragma unroll
    for (int u = 0; u < 64; ++u) {
        float4 e4 = ef[u];
        float4 zz = zf4[u];
        float p0 = zz.x * e4.x; asm("" : "+v"(p0)); a0 += p0;
        float p1 = zz.y * e4.y; asm("" : "+v"(p1)); a1 += p1;
        float p2 = zz.z * e4.z; asm("" : "+v"(p2)); a2 += p2;
        float p3 = zz.w * e4.w; asm("" : "+v"(p3)); a3 += p3;
    }
    float t1 = a0 + a1;
    float t2 = a2 + a3;
    float Pn = t1 + t2;                 // fl(fl(A0+A1)+fl(A2+A3))
    return s1v - 2.0f * Pn;             // fl(S1 - 2P), S2 absorbed
}

// ---------------- prep: Z -> Zt fp32 + hi/lo bf16 [16384][256] (transposed) ----------------
__global__ void k_prep_z(const float* __restrict__ Z, float* __restrict__ Zt,
                         unsigned short* __restrict__ Zh, unsigned short* __restrict__ Zl) {
    __shared__ float tile[32][33];
    const int blk = blockIdx.x;          // b*512 + ct*64 + mt
    const int mt = blk & 63;
    const int ct = (blk >> 6) & 7;
    const int b  = blk >> 9;
    const int t = threadIdx.x, tr = t >> 5, tc = t & 31;
#pragma unroll
    for (int rr = 0; rr < 4; ++rr) {
        int cl = tr + rr * 8;
        tile[cl][tc] = Z[b * 524288 + (ct * 32 + cl) * 2048 + mt * 32 + tc]; // coalesced (m)
    }
    __syncthreads();
#pragma unroll
    for (int rr = 0; rr < 4; ++rr) {
        int nl = tr + rr * 8;                 // m_local
        float x = tile[tc][nl];
        unsigned short h = bf16_rne(x);
        float hf = __uint_as_float((unsigned)h << 16);
        unsigned short lo = bf16_rne(x - hf);
        int n = b * 2048 + mt * 32 + nl;
        Zt[n * 256 + ct * 32 + tc] = x;       // coalesced (c)
        Zh[n * 256 + ct * 32 + tc] = h;
        Zl[n * 256 + ct * 32 + tc] = lo;
    }
}

// ---------------- prep: E -> hi/lo bf16 [8192][256] ----------------
__global__ void k_prep_e(const float* __restrict__ E, unsigned short* __restrict__ Eh,
                         unsigned short* __restrict__ El) {
    const int g = blockIdx.x * 256 + threadIdx.x;      // 524288 float4's
    float4 v = reinterpret_cast<const float4*>(E)[g];
    ushort4 h, lo;
    h.x = bf16_rne(v.x); h.y = bf16_rne(v.y); h.z = bf16_rne(v.z); h.w = bf16_rne(v.w);
    lo.x = bf16_rne(v.x - __uint_as_float((unsigned)h.x << 16));
    lo.y = bf16_rne(v.y - __uint_as_float((unsigned)h.y << 16));
    lo.z = bf16_rne(v.z - __uint_as_float((unsigned)h.z << 16));
    lo.w = bf16_rne(v.w - __uint_as_float((unsigned)h.w << 16));
    reinterpret_cast<ushort4*>(Eh)[g] = h;
    reinterpret_cast<ushort4*>(El)[g] = lo;
}

// ---------------- A-resident MFMA screen ----------------
// Grid 1024: kr = bid&7 (1024-k range, XCD-local B panel), nt = bid>>3 (128 rows).
// A-frags (z hi/lo) for all K=256 live in VGPRs, loaded once from global.
// B streams via one 32KB XOR-swizzled LDS buffer, 64-c chunks (BK=64), 32 steps.
// bf16 double-split: P = hh + hl + lh (err ~1e-7). Epilogue: per-wave top-2 +
// argmin over the 128-col tile -> partrec[n][kt] = (m1, m2, k1), u = -P units.
// Frag layout [m89-verified]: A/B lane l -> row l&15, c-slice (l>>4)*8;
// C/D: col = lane&15, row = (lane>>4)*4 + reg.
__launch_bounds__(256, 2)
__global__ void k_screen(const unsigned short* __restrict__ Zh, const unsigned short* __restrict__ Zl,
                         const unsigned short* __restrict__ Eh, const unsigned short* __restrict__ El,
                         float4* __restrict__ partrec) {
    __shared__ __align__(16) char lds[32768];   // [2 arrays][128 kcol][64 c] bf16, swizzled
    const int t = threadIdx.x;
    const int kr = blockIdx.x & 7;
    const int nt = blockIdx.x >> 3;
    const int n0 = nt * 128;
    const int w = t >> 6, l = t & 63;
    const int l15 = l & 15, lh = l >> 4;

    // one-time A-fragment load (rows n0 + w*32 + mf*16 + l15; c = s*32 + lh*8)
    short8 Ah[2][8], Al[2][8];
#pragma unroll
    for (int mf = 0; mf < 2; ++mf) {
        const size_t rowoff = (size_t)(n0 + w * 32 + mf * 16 + l15) * 256 + lh * 8;
#pragma unroll
        for (int s = 0; s < 8; ++s) {
            Ah[mf][s] = *(const short8*)(Zh + rowoff + s * 32);
            Al[mf][s] = *(const short8*)(Zl + rowoff + s * 32);
        }
    }

    f32x4 acc[2][8];
#pragma unroll
    for (int mf = 0; mf < 2; ++mf)
#pragma unroll
        for (int nf = 0; nf < 8; ++nf) acc[mf][nf] = (f32x4)(0.0f);

    for (int step = 0; step < 32; ++step) {
        const int kt = step >> 2, kb = step & 3;
        const int k0 = kr * 1024 + kt * 128;

        __syncthreads();
        // stage B chunk: [hi|lo][128 kcol][64 c]; thread stages 8 x 16B granules
        u16x8 breg[8];
#pragma unroll
        for (int i = 0; i < 8; ++i) {
            const int gid = i * 256 + t;
            const int row = (gid >> 3) & 127, gc = gid & 7;
            const unsigned short* src = (gid >> 10 ? El : Eh);
            breg[i] = *(const u16x8*)(src + (size_t)(k0 + row) * 256 + kb * 64 + gc * 8);
        }
#pragma unroll
        for (int i = 0; i < 8; ++i) {
            const int gid = i * 256 + t;
            const int arr = gid >> 10, row = (gid >> 3) & 127, gc = gid & 7;
            *(u16x8*)(lds + arr * 16384 + row * 128 + ((gc * 16) ^ ((row & 7) << 4))) = breg[i];
        }
        __syncthreads();

#pragma unroll
        for (int ks = 0; ks < 2; ++ks) {
            const int cb = ks * 64 + (lh << 4);
            const int s = kb * 2 + ks;
#pragma unroll
            for (int nf = 0; nf < 8; ++nf) {
                const int br = nf * 16 + l15;
                const int off = br * 128 + (cb ^ ((br & 7) << 4));
                short8 bh = *(const short8*)(lds + off);
                short8 bl = *(const short8*)(lds + 16384 + off);
#pragma unroll
                for (int mf = 0; mf < 2; ++mf) {
                    acc[mf][nf] = __builtin_amdgcn_mfma_f32_16x16x32_bf16(Ah[mf][s], bh, acc[mf][nf], 0, 0, 0);
                    acc[mf][nf] = __builtin_amdgcn_mfma_f32_16x16x32_bf16(Ah[mf][s], bl, acc[mf][nf], 0, 0, 0);
                    acc[mf][nf] = __builtin_amdgcn_mfma_f32_16x16x32_bf16(Al[mf][s], bh, acc[mf][nf], 0, 0, 0);
                }
            }
        }

        if (kb == 3) {
            // epilogue: top-2 + argmin over this k-tile's 128 cols, per n-row
            const int kbase = k0 + l15;
#pragma unroll
            for (int mf = 0; mf < 2; ++mf) {
#pragma unroll
                for (int q = 0; q < 4; ++q) {
                    float m1 = -acc[mf][0][q];
                    int k1 = kbase;
                    float m2 = INFINITY;
#pragma unroll
                    for (int nf = 1; nf < 8; ++nf) {
                        float v = -acc[mf][nf][q];
                        if (v < m1) { m2 = m1; m1 = v; k1 = kbase + nf * 16; }
                        else m2 = fminf(m2, v);
                    }
#pragma unroll
                    for (int o = 1; o < 16; o <<= 1) {
                        float om1 = __shfl_xor(m1, o);
                        float om2 = __shfl_xor(m2, o);
                        int   ok  = __shfl_xor(k1, o);
                        float hi = fmaxf(m1, om1);
                        if (om1 < m1) { m1 = om1; k1 = ok; }
                        m2 = fminf(fminf(m2, om2), hi);
                    }
                    if (l15 == 0) {
                        const int n = n0 + w * 32 + mf * 16 + lh * 4 + q;
                        partrec[(size_t)n * NCH + (kr * 8 + kt)] =
                            make_float4(m1, m2, __int_as_float(k1), 0.0f);
                    }
                }
#pragma unroll
                for (int nf = 0; nf < 8; ++nf) acc[mf][nf] = (f32x4)(0.0f);
            }
        }
    }
}

// ---------------- rescue: exact np-emulation on nominated candidates ----------------
// one wave per row. Computes exact-np S1 in-wave (numpy pairwise over the staged
// z row). Path A: chunk-argmin candidates. Path B: full-chunk fp32 re-screen when
// chunk 2nd-min also within margin. Emits idx + fp64 ||z-e*||^2 for the loss.
__global__ void k_rescue(const float* __restrict__ Zt, const float* __restrict__ E,
                         const float4* __restrict__ partrec,
                         int* __restrict__ idxv, double* __restrict__ dmin,
                         float* __restrict__ out) {
#pragma clang fp contract(off)
    __shared__ __align__(16) float zsm[4][256];
    const int t = threadIdx.x;
    const int r = t >> 6;            // wave id = row within block
    const int lane = t & 63;
    const int n = blockIdx.x * 4 + r;

    // stage z row (coalesced float4 from transposed Zt)
    reinterpret_cast<float4*>(zsm[r])[lane] =
        reinterpret_cast<const float4*>(Zt)[(size_t)n * 64 + lane];
    __syncthreads();

    const float4* zf4 = reinterpret_cast<const float4*>(zsm[r]);

    // exact-np S1: two 128-halves, 8 chains each (lane = h*8+j), tree-combined
    float ch = 0.0f;
    if (lane < 16) {
        const int h = lane >> 3, j = lane & 7;
        for (int t2 = 0; t2 < 16; ++t2) {
            float z = zsm[r][h * 128 + t2 * 8 + j];
            float w = z * z;
            asm("" : "+v"(w));
            ch += w;
        }
    }
    ch += __shfl_xor(ch, 1);   // (r0+r1) etc., commutative-safe
    ch += __shfl_xor(ch, 2);   // ((r0+r1)+(r2+r3))
    ch += __shfl_xor(ch, 4);   // full 8-chain tree = blk[h]
    ch += __shfl_xor(ch, 8);   // lane0: blk0 + blk1
    const float s1v = __shfl(ch, 0);

    float4 rec = partrec[(size_t)n * NCH + lane];     // lane == chunk
    float pm1 = rec.x, pm2 = rec.y;
    int pk = __float_as_int(rec.z);

    float rowm = pm1;
#pragma unroll
    for (int o = 1; o < 64; o <<= 1) rowm = fminf(rowm, __shfl_xor(rowm, o));

    unsigned long long best = 0xFFFFFFFFFFFFFFFFull;

    // Path A: emulate this chunk's argmin if within margin
    if (pm1 <= rowm + U_MARGIN) {
        const float4* ef = reinterpret_cast<const float4*>(E + (size_t)pk * 256);
        float d = np_dist(zf4, ef, s1v);
        best = ((unsigned long long)__float_as_uint(d) << 32) | (unsigned)pk;
    }

    // Path B: full re-screen of chunks whose 2nd-min is also within margin
    unsigned long long qm = __ballot(pm2 <= rowm + CH_MARGIN);
    while (qm) {
        const int chk = __ffsll(qm) - 1;
        qm &= qm - 1;
        const int c0 = chk * CHK;
#pragma unroll 1
        for (int s = 0; s < 2; ++s) {
            const int k = c0 + s * 64 + lane;
            const float4* ef = reinterpret_cast<const float4*>(E + (size_t)k * 256);
            float ax = 0.f, ay = 0.f, az = 0.f, aw = 0.f;
#pragma unroll
            for (int u = 0; u < 64; ++u) {
                float4 e4 = ef[u];
                float4 zz = zf4[u];
                ax = fmaf(zz.x, e4.x, ax);
                ay = fmaf(zz.y, e4.y, ay);
                az = fmaf(zz.z, e4.z, az);
                aw = fmaf(zz.w, e4.w, aw);
            }
            const float uk = -((ax + ay) + (az + aw));
            if (uk <= rowm + U_MARGIN) {
                float d = np_dist(zf4, ef, s1v);
                unsigned long long pkd =
                    ((unsigned long long)__float_as_uint(d) << 32) | (unsigned)k;
                if (pkd < best) best = pkd;
            }
        }
    }

    // wave-reduce lexicographic min of (d, k)
#pragma unroll
    for (int o = 32; o; o >>= 1) {
        unsigned lo = (unsigned)(best & 0xFFFFFFFFull);
        unsigned hi = (unsigned)(best >> 32);
        unsigned olo = __shfl_xor(lo, o);
        unsigned ohi = __shfl_xor(hi, o);
        unsigned long long ob = ((unsigned long long)ohi << 32) | olo;
        if (ob < best) best = ob;
    }
    const int besti = (int)(best & 0xFFFFFFFFull);

    // fp64 ||z - e_best||^2 (for the loss)
    {
        float4 e4 = reinterpret_cast<const float4*>(E + (size_t)besti * 256)[lane];
        float4 zz = zf4[lane];
        double d0 = (double)zz.x - (double)e4.x;
        double d1 = (double)zz.y - (double)e4.y;
        double d2 = (double)zz.z - (double)e4.z;
        double d3 = (double)zz.w - (double)e4.w;
        double d = d0 * d0 + d1 * d1 + d2 * d2 + d3 * d3;
#pragma unroll
        for (int o = 32; o; o >>= 1) d += __shfl_xor(d, o);
        if (lane == 0) {
            idxv[n] = besti;
            out[OUT_IDX + n] = (float)besti;
            dmin[n] = d;
        }
    }
}

// ---------------- gather z_q with LDS transpose ----------------
__global__ void k_gather(const float* __restrict__ emb, const int* __restrict__ idxv,
                         float* __restrict__ out) {
    __shared__ float tile[32][33];
    __shared__ int kidx[32];
    const int blk = blockIdx.x;
    const int ct = blk & 7;
    const int mt = (blk >> 3) & 63;
    const int b = blk >> 9;
    const int t = threadIdx.x, tr = t >> 5, tc = t & 31;

    if (t < 32) kidx[t] = idxv[b * 2048 + mt * 32 + t];
    __syncthreads();
#pragma unroll
    for (int rr = 0; rr < 4; ++rr) {
        int row = tr + rr * 8;
        tile[row][tc] = emb[kidx[row] * 256 + ct * 32 + tc];
    }
    __syncthreads();
#pragma unroll
    for (int rr = 0; rr < 4; ++rr) {
        int cl = tr + rr * 8;
        out[b * 524288 + (ct * 32 + cl) * 2048 + mt * 32 + tc] = tile[tc][cl];
    }
}

// ---------------- final loss reduce ----------------
__global__ void k_loss(const double* __restrict__ dmin, float* __restrict__ out) {
    __shared__ double sm[256];
    double s = 0.0;
    for (int i = threadIdx.x; i < NROWS; i += 256) s += dmin[i];
    sm[threadIdx.x] = s;
    __syncthreads();
    for (int o = 128; o; o >>= 1) {
        if (threadIdx.x < o) sm[threadIdx.x] += sm[threadIdx.x + o];
        __syncthreads();
    }
    if (threadIdx.x == 0)
        out[OUT_LOSS] = (float)(1.25 * sm[0] / 4194304.0);
}

// ---------------- launch ----------------
extern "C" void kernel_launch(void* const* d_in, const int* in_sizes, int n_in,
                              void* d_out, int out_size, void* d_ws, size_t ws_size,
                              hipStream_t stream) {
    const float* Z = (const float*)d_in[0];   // [8,256,8,16,16] fp32
    const float* E = (const float*)d_in[1];   // [8192,256] fp32
    float* out = (float*)d_out;
    char* ws = (char*)d_ws;

    size_t o = 0;
    double* dmin    = (double*)(ws + o); o += 128 << 10;
    int*    idxv    = (int*)(ws + o);    o += 64 << 10;
    float4* partrec = (float4*)(ws + o); o += (size_t)NROWS * NCH * 16;            // 16 MB
    float*  Zt      = (float*)(ws + o);  o += (size_t)NROWS * 256 * 4;             // 16 MB
    unsigned short* Zh = (unsigned short*)(ws + o); o += (size_t)NROWS * 256 * 2;  // 8 MB
    unsigned short* Zl = (unsigned short*)(ws + o); o += (size_t)NROWS * 256 * 2;  // 8 MB
    unsigned short* Eh = (unsigned short*)(ws + o); o += (size_t)NE * 256 * 2;     // 4 MB
    unsigned short* El = (unsigned short*)(ws + o); o += (size_t)NE * 256 * 2;     // 4 MB

    hipLaunchKernelGGL(k_prep_z, dim3(4096), dim3(256), 0, stream, Z, Zt, Zh, Zl);
    hipLaunchKernelGGL(k_prep_e, dim3(2048), dim3(256), 0, stream, E, Eh, El);
    hipLaunchKernelGGL(k_screen, dim3(1024), dim3(256), 0, stream, Zh, Zl, Eh, El, partrec);
    hipLaunchKernelGGL(k_rescue, dim3(4096), dim3(256), 0, stream, Zt, E,
                       partrec, idxv, dmin, out);
    hipLaunchKernelGGL(k_gather, dim3(4096), dim3(256), 0, stream, E, idxv, out);
    hipLaunchKernelGGL(k_loss,   dim3(1),    dim3(256), 0, stream, dmin, out);
}

// Round 9
// 518.768 us; speedup vs baseline: 1.1305x; 1.1305x over previous
//
#include <hip/hip_runtime.h>

// Problem constants
#define NROWS 16384      // 8 * (8*16*16)
#define NE 8192
#define NCH 64           // k-chunks per row (chunk = 128 k's)
#define CHK 128
#define OUT_LOSS 4194304
#define OUT_IDX  4194305

#define U_MARGIN  2.5e-5f   // u-space np-gap ulp(S1)/2 = 1.53e-5 + screen err + slack
#define CH_MARGIN 3.0e-5f

typedef __attribute__((ext_vector_type(8))) short short8;
typedef __attribute__((ext_vector_type(8))) unsigned short u16x8;
typedef __attribute__((ext_vector_type(4))) float f32x4;

__device__ inline unsigned short bf16_rne(float f) {
    unsigned u = __float_as_uint(f);
    return (unsigned short)((u + 0x7FFFu + ((u >> 16) & 1u)) >> 16);
}

// exact np SSE 4-chain emulation of fl(S1 - 2*P) (sequential, no fma, no reassoc)
__device__ inline float np_dist(const float4* __restrict__ zf4,
                                const float4* __restrict__ ef, float s1v) {
#pragma clang fp contract(off)
    float a0 = 0.f, a1 = 0.f, a2 = 0.f, a3 = 0.f;
#pragma unroll
    for (int u = 0; u < 64; ++u) {
        float4 e4 = ef[u];
        float4 zz = zf4[u];
        float p0 = zz.x * e4.x; asm("" : "+v"(p0)); a0 += p0;
        float p1 = zz.y * e4.y; asm("" : "+v"(p1)); a1 += p1;
        float p2 = zz.z * e4.z; asm("" : "+v"(p2)); a2 += p2;
        float p3 = zz.w * e4.w; asm("" : "+v"(p3)); a3 += p3;
    }
    float t1 = a0 + a1;
    float t2 = a2 + a3;
    float Pn = t1 + t2;                 // fl(fl(A0+A1)+fl(A2+A3))
    return s1v - 2.0f * Pn;             // fl(S1 - 2P), S2 absorbed
}

// ---------------- prep: Z -> Zt fp32 + hi/lo bf16 [16384][256] (transposed) ----------------
__global__ void k_prep_z(const float* __restrict__ Z, float* __restrict__ Zt,
                         unsigned short* __restrict__ Zh, unsigned short* __restrict__ Zl) {
    __shared__ float tile[32][33];
    const int blk = blockIdx.x;          // b*512 + ct*64 + mt
    const int mt = blk & 63;
    const int ct = (blk >> 6) & 7;
    const int b  = blk >> 9;
    const int t = threadIdx.x, tr = t >> 5, tc = t & 31;
#pragma unroll
    for (int rr = 0; rr < 4; ++rr) {
        int cl = tr + rr * 8;
        tile[cl][tc] = Z[b * 524288 + (ct * 32 + cl) * 2048 + mt * 32 + tc]; // coalesced (m)
    }
    __syncthreads();
#pragma unroll
    for (int rr = 0; rr < 4; ++rr) {
        int nl = tr + rr * 8;                 // m_local
        float x = tile[tc][nl];
        unsigned short h = bf16_rne(x);
        float hf = __uint_as_float((unsigned)h << 16);
        unsigned short lo = bf16_rne(x - hf);
        int n = b * 2048 + mt * 32 + nl;
        Zt[n * 256 + ct * 32 + tc] = x;       // coalesced (c)
        Zh[n * 256 + ct * 32 + tc] = h;
        Zl[n * 256 + ct * 32 + tc] = lo;
    }
}

// ---------------- prep: E -> hi/lo bf16 [8192][256] ----------------
__global__ void k_prep_e(const float* __restrict__ E, unsigned short* __restrict__ Eh,
                         unsigned short* __restrict__ El) {
    const int g = blockIdx.x * 256 + threadIdx.x;      // 524288 float4's
    float4 v = reinterpret_cast<const float4*>(E)[g];
    ushort4 h, lo;
    h.x = bf16_rne(v.x); h.y = bf16_rne(v.y); h.z = bf16_rne(v.z); h.w = bf16_rne(v.w);
    lo.x = bf16_rne(v.x - __uint_as_float((unsigned)h.x << 16));
    lo.y = bf16_rne(v.y - __uint_as_float((unsigned)h.y << 16));
    lo.z = bf16_rne(v.z - __uint_as_float((unsigned)h.z << 16));
    lo.w = bf16_rne(v.w - __uint_as_float((unsigned)h.w << 16));
    reinterpret_cast<ushort4*>(Eh)[g] = h;
    reinterpret_cast<ushort4*>(El)[g] = lo;
}

// ---------------- A-resident MFMA screen ----------------
// Grid 1024: kr = bid&7 (1024-k range, XCD-local B panel), nt = bid>>3 (128 rows).
// A-frags (z hi/lo) for all K=256 live in VGPRs, loaded once from global.
// ALL Ah/Al indices are compile-time (kb/ks fully unrolled) — rule #20: runtime
// indices would demote the arrays to scratch (the round-8 pathology).
// B streams via one 32KB XOR-swizzled LDS buffer, 64-c chunks (BK=64).
// bf16 double-split: P = hh + hl + lh (err ~1e-7). Epilogue per 128-k tile:
// per-row top-2 + argmin -> partrec[n][kt] = (m1, m2, k1), u = -P units.
// Frag layout [m89-verified]: A/B lane l -> row l&15, c-slice (l>>4)*8;
// C/D: col = lane&15, row = (lane>>4)*4 + reg.
__launch_bounds__(256, 2)
__global__ void k_screen(const unsigned short* __restrict__ Zh, const unsigned short* __restrict__ Zl,
                         const unsigned short* __restrict__ Eh, const unsigned short* __restrict__ El,
                         float4* __restrict__ partrec) {
    __shared__ __align__(16) char lds[32768];   // [2 arrays][128 kcol][64 c] bf16, swizzled
    const int t = threadIdx.x;
    const int kr = blockIdx.x & 7;
    const int nt = blockIdx.x >> 3;
    const int n0 = nt * 128;
    const int w = t >> 6, l = t & 63;
    const int l15 = l & 15, lh = l >> 4;

    // one-time A-fragment load (rows n0 + w*32 + mf*16 + l15; c = s*32 + lh*8)
    short8 Ah[2][8], Al[2][8];
#pragma unroll
    for (int mf = 0; mf < 2; ++mf) {
        const size_t rowoff = (size_t)(n0 + w * 32 + mf * 16 + l15) * 256 + lh * 8;
#pragma unroll
        for (int s = 0; s < 8; ++s) {
            Ah[mf][s] = *(const short8*)(Zh + rowoff + s * 32);
            Al[mf][s] = *(const short8*)(Zl + rowoff + s * 32);
        }
    }

    f32x4 acc[2][8];
#pragma unroll
    for (int mf = 0; mf < 2; ++mf)
#pragma unroll
        for (int nf = 0; nf < 8; ++nf) acc[mf][nf] = (f32x4)(0.0f);

    for (int kt = 0; kt < 8; ++kt) {           // runtime loop: only feeds addresses
        const int k0 = kr * 1024 + kt * 128;

#pragma unroll
        for (int kb = 0; kb < 4; ++kb) {       // unrolled: kb is compile-time
            __syncthreads();
            // stage B chunk: [hi|lo][128 kcol][64 c]; thread stages 8 x 16B granules
            u16x8 breg[8];
#pragma unroll
            for (int i = 0; i < 8; ++i) {
                const int gid = i * 256 + t;
                const int row = (gid >> 3) & 127, gc = gid & 7;
                const unsigned short* src = (gid >> 10 ? El : Eh);
                breg[i] = *(const u16x8*)(src + (size_t)(k0 + row) * 256 + kb * 64 + gc * 8);
            }
#pragma unroll
            for (int i = 0; i < 8; ++i) {
                const int gid = i * 256 + t;
                const int arr = gid >> 10, row = (gid >> 3) & 127, gc = gid & 7;
                *(u16x8*)(lds + arr * 16384 + row * 128 + ((gc * 16) ^ ((row & 7) << 4))) = breg[i];
            }
            __syncthreads();

#pragma unroll
            for (int ks = 0; ks < 2; ++ks) {   // unrolled: s = kb*2+ks compile-time
                const int cb = ks * 64 + (lh << 4);
#pragma unroll
                for (int nf = 0; nf < 8; ++nf) {
                    const int br = nf * 16 + l15;
                    const int off = br * 128 + (cb ^ ((br & 7) << 4));
                    short8 bh = *(const short8*)(lds + off);
                    short8 bl = *(const short8*)(lds + 16384 + off);
#pragma unroll
                    for (int mf = 0; mf < 2; ++mf) {
                        acc[mf][nf] = __builtin_amdgcn_mfma_f32_16x16x32_bf16(Ah[mf][kb * 2 + ks], bh, acc[mf][nf], 0, 0, 0);
                        acc[mf][nf] = __builtin_amdgcn_mfma_f32_16x16x32_bf16(Ah[mf][kb * 2 + ks], bl, acc[mf][nf], 0, 0, 0);
                        acc[mf][nf] = __builtin_amdgcn_mfma_f32_16x16x32_bf16(Al[mf][kb * 2 + ks], bh, acc[mf][nf], 0, 0, 0);
                    }
                }
            }
        }

        // epilogue: top-2 + argmin over this k-tile's 128 cols, per n-row
        const int kbase = k0 + l15;
#pragma unroll
        for (int mf = 0; mf < 2; ++mf) {
#pragma unroll
            for (int q = 0; q < 4; ++q) {
                float m1 = -acc[mf][0][q];
                int k1 = kbase;
                float m2 = INFINITY;
#pragma unroll
                for (int nf = 1; nf < 8; ++nf) {
                    float v = -acc[mf][nf][q];
                    if (v < m1) { m2 = m1; m1 = v; k1 = kbase + nf * 16; }
                    else m2 = fminf(m2, v);
                }
#pragma unroll
                for (int o = 1; o < 16; o <<= 1) {
                    float om1 = __shfl_xor(m1, o);
                    float om2 = __shfl_xor(m2, o);
                    int   ok  = __shfl_xor(k1, o);
                    float hi = fmaxf(m1, om1);
                    if (om1 < m1) { m1 = om1; k1 = ok; }
                    m2 = fminf(fminf(m2, om2), hi);
                }
                if (l15 == 0) {
                    const int n = n0 + w * 32 + mf * 16 + lh * 4 + q;
                    partrec[(size_t)n * NCH + (kr * 8 + kt)] =
                        make_float4(m1, m2, __int_as_float(k1), 0.0f);
                }
            }
#pragma unroll
            for (int nf = 0; nf < 8; ++nf) acc[mf][nf] = (f32x4)(0.0f);
        }
    }
}

// ---------------- rescue: exact np-emulation on nominated candidates ----------------
// one wave per row. Computes exact-np S1 in-wave (numpy pairwise over the staged
// z row). Path A: chunk-argmin candidates. Path B: full-chunk fp32 re-screen when
// chunk 2nd-min also within margin. Emits idx + fp64 ||z-e*||^2 for the loss.
__global__ void k_rescue(const float* __restrict__ Zt, const float* __restrict__ E,
                         const float4* __restrict__ partrec,
                         int* __restrict__ idxv, double* __restrict__ dmin,
                         float* __restrict__ out) {
#pragma clang fp contract(off)
    __shared__ __align__(16) float zsm[4][256];
    const int t = threadIdx.x;
    const int r = t >> 6;            // wave id = row within block
    const int lane = t & 63;
    const int n = blockIdx.x * 4 + r;

    // stage z row (coalesced float4 from transposed Zt)
    reinterpret_cast<float4*>(zsm[r])[lane] =
        reinterpret_cast<const float4*>(Zt)[(size_t)n * 64 + lane];
    __syncthreads();

    const float4* zf4 = reinterpret_cast<const float4*>(zsm[r]);

    // exact-np S1: two 128-halves, 8 chains each (lane = h*8+j), tree-combined
    float ch = 0.0f;
    if (lane < 16) {
        const int h = lane >> 3, j = lane & 7;
        for (int t2 = 0; t2 < 16; ++t2) {
            float z = zsm[r][h * 128 + t2 * 8 + j];
            float w = z * z;
            asm("" : "+v"(w));
            ch += w;
        }
    }
    ch += __shfl_xor(ch, 1);   // (r0+r1) etc., commutative-safe
    ch += __shfl_xor(ch, 2);   // ((r0+r1)+(r2+r3))
    ch += __shfl_xor(ch, 4);   // full 8-chain tree = blk[h]
    ch += __shfl_xor(ch, 8);   // lane0: blk0 + blk1
    const float s1v = __shfl(ch, 0);

    float4 rec = partrec[(size_t)n * NCH + lane];     // lane == chunk
    float pm1 = rec.x, pm2 = rec.y;
    int pk = __float_as_int(rec.z);

    float rowm = pm1;
#pragma unroll
    for (int o = 1; o < 64; o <<= 1) rowm = fminf(rowm, __shfl_xor(rowm, o));

    unsigned long long best = 0xFFFFFFFFFFFFFFFFull;

    // Path A: emulate this chunk's argmin if within margin
    if (pm1 <= rowm + U_MARGIN) {
        const float4* ef = reinterpret_cast<const float4*>(E + (size_t)pk * 256);
        float d = np_dist(zf4, ef, s1v);
        best = ((unsigned long long)__float_as_uint(d) << 32) | (unsigned)pk;
    }

    // Path B: full re-screen of chunks whose 2nd-min is also within margin
    unsigned long long qm = __ballot(pm2 <= rowm + CH_MARGIN);
    while (qm) {
        const int chk = __ffsll(qm) - 1;
        qm &= qm - 1;
        const int c0 = chk * CHK;
#pragma unroll 1
        for (int s = 0; s < 2; ++s) {
            const int k = c0 + s * 64 + lane;
            const float4* ef = reinterpret_cast<const float4*>(E + (size_t)k * 256);
            float ax = 0.f, ay = 0.f, az = 0.f, aw = 0.f;
#pragma unroll
            for (int u = 0; u < 64; ++u) {
                float4 e4 = ef[u];
                float4 zz = zf4[u];
                ax = fmaf(zz.x, e4.x, ax);
                ay = fmaf(zz.y, e4.y, ay);
                az = fmaf(zz.z, e4.z, az);
                aw = fmaf(zz.w, e4.w, aw);
            }
            const float uk = -((ax + ay) + (az + aw));
            if (uk <= rowm + U_MARGIN) {
                float d = np_dist(zf4, ef, s1v);
                unsigned long long pkd =
                    ((unsigned long long)__float_as_uint(d) << 32) | (unsigned)k;
                if (pkd < best) best = pkd;
            }
        }
    }

    // wave-reduce lexicographic min of (d, k)
#pragma unroll
    for (int o = 32; o; o >>= 1) {
        unsigned lo = (unsigned)(best & 0xFFFFFFFFull);
        unsigned hi = (unsigned)(best >> 32);
        unsigned olo = __shfl_xor(lo, o);
        unsigned ohi = __shfl_xor(hi, o);
        unsigned long long ob = ((unsigned long long)ohi << 32) | olo;
        if (ob < best) best = ob;
    }
    const int besti = (int)(best & 0xFFFFFFFFull);

    // fp64 ||z - e_best||^2 (for the loss)
    {
        float4 e4 = reinterpret_cast<const float4*>(E + (size_t)besti * 256)[lane];
        float4 zz = zf4[lane];
        double d0 = (double)zz.x - (double)e4.x;
        double d1 = (double)zz.y - (double)e4.y;
        double d2 = (double)zz.z - (double)e4.z;
        double d3 = (double)zz.w - (double)e4.w;
        double d = d0 * d0 + d1 * d1 + d2 * d2 + d3 * d3;
#pragma unroll
        for (int o = 32; o; o >>= 1) d += __shfl_xor(d, o);
        if (lane == 0) {
            idxv[n] = besti;
            out[OUT_IDX + n] = (float)besti;
            dmin[n] = d;
        }
    }
}

// ---------------- gather z_q with LDS transpose ----------------
__global__ void k_gather(const float* __restrict__ emb, const int* __restrict__ idxv,
                         float* __restrict__ out) {
    __shared__ float tile[32][33];
    __shared__ int kidx[32];
    const int blk = blockIdx.x;
    const int ct = blk & 7;
    const int mt = (blk >> 3) & 63;
    const int b = blk >> 9;
    const int t = threadIdx.x, tr = t >> 5, tc = t & 31;

    if (t < 32) kidx[t] = idxv[b * 2048 + mt * 32 + t];
    __syncthreads();
#pragma unroll
    for (int rr = 0; rr < 4; ++rr) {
        int row = tr + rr * 8;
        tile[row][tc] = emb[kidx[row] * 256 + ct * 32 + tc];
    }
    __syncthreads();
#pragma unroll
    for (int rr = 0; rr < 4; ++rr) {
        int cl = tr + rr * 8;
        out[b * 524288 + (ct * 32 + cl) * 2048 + mt * 32 + tc] = tile[tc][cl];
    }
}

// ---------------- final loss reduce ----------------
__global__ void k_loss(const double* __restrict__ dmin, float* __restrict__ out) {
    __shared__ double sm[256];
    double s = 0.0;
    for (int i = threadIdx.x; i < NROWS; i += 256) s += dmin[i];
    sm[threadIdx.x] = s;
    __syncthreads();
    for (int o = 128; o; o >>= 1) {
        if (threadIdx.x < o) sm[threadIdx.x] += sm[threadIdx.x + o];
        __syncthreads();
    }
    if (threadIdx.x == 0)
        out[OUT_LOSS] = (float)(1.25 * sm[0] / 4194304.0);
}

// ---------------- launch ----------------
extern "C" void kernel_launch(void* const* d_in, const int* in_sizes, int n_in,
                              void* d_out, int out_size, void* d_ws, size_t ws_size,
                              hipStream_t stream) {
    const float* Z = (const float*)d_in[0];   // [8,256,8,16,16] fp32
    const float* E = (const float*)d_in[1];   // [8192,256] fp32
    float* out = (float*)d_out;
    char* ws = (char*)d_ws;

    size_t o = 0;
    double* dmin    = (double*)(ws + o); o += 128 << 10;
    int*    idxv    = (int*)(ws + o);    o += 64 << 10;
    float4* partrec = (float4*)(ws + o); o += (size_t)NROWS * NCH * 16;            // 16 MB
    float*  Zt      = (float*)(ws + o);  o += (size_t)NROWS * 256 * 4;             // 16 MB
    unsigned short* Zh = (unsigned short*)(ws + o); o += (size_t)NROWS * 256 * 2;  // 8 MB
    unsigned short* Zl = (unsigned short*)(ws + o); o += (size_t)NROWS * 256 * 2;  // 8 MB
    unsigned short* Eh = (unsigned short*)(ws + o); o += (size_t)NE * 256 * 2;     // 4 MB
    unsigned short* El = (unsigned short*)(ws + o); o += (size_t)NE * 256 * 2;     // 4 MB

    hipLaunchKernelGGL(k_prep_z, dim3(4096), dim3(256), 0, stream, Z, Zt, Zh, Zl);
    hipLaunchKernelGGL(k_prep_e, dim3(2048), dim3(256), 0, stream, E, Eh, El);
    hipLaunchKernelGGL(k_screen, dim3(1024), dim3(256), 0, stream, Zh, Zl, Eh, El, partrec);
    hipLaunchKernelGGL(k_rescue, dim3(4096), dim3(256), 0, stream, Zt, E,
                       partrec, idxv, dmin, out);
    hipLaunchKernelGGL(k_gather, dim3(4096), dim3(256), 0, stream, E, idxv, out);
    hipLaunchKernelGGL(k_loss,   dim3(1),    dim3(256), 0, stream, dmin, out);
}